// Round 4
// baseline (6498.525 us; speedup 1.0000x reference)
//
#include <hip/hip_runtime.h>
#include <hip/hip_bf16.h>

// Problem constants
#define BB 16
#define CIN 7
#define CH 32
#define HH 256
#define WW 256
#define PLANE (HH*WW)                   // 65536
#define YELEMS ((size_t)BB*CH*PLANE)    // 33,554,432 floats = 128 MiB

typedef _Float16 half2v __attribute__((ext_vector_type(2)));
typedef _Float16 half8  __attribute__((ext_vector_type(8)));
typedef float    float4v __attribute__((ext_vector_type(4)));

__device__ __forceinline__ float fast_tanh(float x) {
    float xc = fminf(fmaxf(x, -15.f), 15.f);
    float e  = __expf(2.f * xc);
    return (e - 1.f) / (e + 1.f);
}

__device__ __forceinline__ unsigned packh2(float a, float b) {
    half2v h;
    h.x = (_Float16)a;
    h.y = (_Float16)b;
    return __builtin_bit_cast(unsigned, h);
}

// Barrier that drains ONLY LDS (lgkmcnt), not global (vmcnt).
// Safe here: the only cross-wave hazard in the step loop is LDS; all global
// Y accesses are lane-private (read-before-write, one touch per column).
// __syncthreads() would add s_waitcnt vmcnt(0) — a 300-700 cyc store-ack
// drain on EVERY step (the m97 barrier lesson).
__device__ __forceinline__ void barrier_lds() {
    asm volatile("s_waitcnt lgkmcnt(0)\n\ts_barrier" ::: "memory");
}

// ---------------------------------------------------------------------------
// Pack scan weights (CH,CH,5) fp32 -> f16 A-fragment order for
// v_mfma_f32_16x16x32_f16.  A[m=lane&15][k=(lane>>4)*8+j], k_global = kt*32+k,
// mapping k_global = tap*32 + ch_in, m -> ch_out = mt*16 + m.
// Flat dword layout per set: (((mt*5 + kt)*64 + lane)*4 + jd), jd packs j=2jd,2jd+1.
__global__ __launch_bounds__(256) void prep_weights(
    unsigned* __restrict__ wA,
    const float* __restrict__ wu, const float* __restrict__ wd,
    const float* __restrict__ wl, const float* __restrict__ wr)
{
    int idx = blockIdx.x * 256 + threadIdx.x;   // dword index [0, 10240)
    if (idx >= 4 * 2560) return;
    int set = idx / 2560;
    int rem = idx % 2560;
    int mt  = rem / 1280;
    int r2  = rem % 1280;
    int kt  = r2 / 256;
    int r3  = r2 % 256;
    int lane = r3 >> 2;
    int jd   = r3 & 3;
    int m    = lane & 15;
    int quad = lane >> 4;
    int ch_out = mt * 16 + m;
    int ch_in0 = quad * 8 + jd * 2;
    const float* src = (set == 0) ? wu : (set == 1) ? wd : (set == 2) ? wl : wr;
    float a = src[(ch_out * CH + ch_in0) * 5 + kt];
    float b = src[(ch_out * CH + ch_in0 + 1) * 5 + kt];
    wA[idx] = packh2(a, b);
}

// ---------------------------------------------------------------------------
// Init conv: Y[b,o,h,x] = tanh( conv3x3(X) + b ), fp32.
__global__ __launch_bounds__(256) void init_conv(
    float* __restrict__ Y, const float* __restrict__ X,
    const float* __restrict__ W, const float* __restrict__ bias)
{
    int bh = blockIdx.x;
    int b  = bh >> 8;
    int h  = bh & 255;
    int x  = threadIdx.x;

    float acc[CH];
    #pragma unroll
    for (int o = 0; o < CH; ++o) acc[o] = bias[o];

    for (int ci = 0; ci < CIN; ++ci) {
        #pragma unroll
        for (int ky = 0; ky < 3; ++ky) {
            int y = h + ky - 1;
            if ((unsigned)y >= (unsigned)HH) continue;
            #pragma unroll
            for (int kx = 0; kx < 3; ++kx) {
                int xx = x + kx - 1;
                float v = ((unsigned)xx < (unsigned)WW)
                          ? X[(((size_t)b * CIN + ci) * HH + y) * WW + xx] : 0.f;
                #pragma unroll
                for (int o = 0; o < CH; ++o)
                    acc[o] = fmaf(v, W[((o * CIN + ci) * 3 + ky) * 3 + kx], acc[o]);
            }
        }
    }
    size_t base = ((size_t)b * CH) * PLANE + (size_t)h * WW + x;
    #pragma unroll
    for (int o = 0; o < CH; ++o)
        Y[base + (size_t)o * PLANE] = fast_tanh(acc[o]);
}

// ---------------------------------------------------------------------------
// MFMA directional scan, in-place on fp32 Y. One block per batch image.
// Per step: C[32ch x 256pos] = W[32 x 160] * im2col(state) via
// v_mfma_f32_16x16x32_f16.  Wave = one 16-pos N-tile; 2 M-tiles x 5 taps.
// Weights persist in regs as A-frags.  State: f16 LDS [row=pos+2][ch],
// pitch 40 halves, double-buffered.  ONE lgkm-only barrier per step;
// X-term prefetched one step ahead; global stores fire-and-forget.
template<int RS, int SS, bool REV>
__global__ __launch_bounds__(1024) void scan_kernel(
    float* __restrict__ Y, const unsigned* __restrict__ wA,
    const float* __restrict__ bias)
{
    constexpr int P = 40;                     // halves per LDS row
    __shared__ _Float16 S[2][260 * P];        // rows: logical pos p at row p+2

    const int tid  = threadIdx.x;
    const int wv   = __builtin_amdgcn_readfirstlane(tid >> 6);
    const int lane = tid & 63;
    const int n    = lane & 15;
    const int quad = lane >> 4;
    const int pos  = wv * 16 + n;

    // --- load persistent A fragments (weights) ---
    half8 afrag[2][5];
    #pragma unroll
    for (int mt = 0; mt < 2; ++mt)
        #pragma unroll
        for (int kt = 0; kt < 5; ++kt) {
            uint4 u = *(const uint4*)(wA + (((mt * 5 + kt) * 64 + lane) << 2));
            afrag[mt][kt] = __builtin_bit_cast(half8, u);
        }

    // --- per-lane bias and global offsets: ch = mt*16 + quad*4 + reg ---
    float bs[2][4];
    size_t gb[2][4];
    float* Yb = Y + (size_t)blockIdx.x * CH * PLANE;
    #pragma unroll
    for (int mt = 0; mt < 2; ++mt)
        #pragma unroll
        for (int r = 0; r < 4; ++r) {
            int ch = mt * 16 + quad * 4 + r;
            bs[mt][r] = bias[ch];
            gb[mt][r] = (size_t)ch * PLANE + (size_t)pos * RS;
        }

    // --- zero pad rows {0,1,258,259} of both buffers ---
    if (tid < 320) {
        int bf  = tid / 160;
        int t   = tid % 160;
        int rr  = t / P;
        int col = t % P;
        int row = (rr < 2) ? rr : (256 + rr);
        S[bf][row * P + col] = (_Float16)0.f;
    }

    // --- initial fill of buf0 with row sp0 (unchanged output row) ---
    {
        const int sp0 = REV ? (HH - 1) : 0;
        int pos0 = tid & 255;
        int cg   = tid >> 8;                  // 0..3 -> channels cg*8..cg*8+7
        float v[8];
        #pragma unroll
        for (int c = 0; c < 8; ++c)
            v[c] = Yb[(size_t)(cg * 8 + c) * PLANE + (size_t)pos0 * RS + (size_t)sp0 * SS];
        uint4 pk;
        pk.x = packh2(v[0], v[1]);
        pk.y = packh2(v[2], v[3]);
        pk.z = packh2(v[4], v[5]);
        pk.w = packh2(v[6], v[7]);
        *(uint4*)&S[0][(pos0 + 2) * P + cg * 8] = pk;
    }
    __syncthreads();

    // --- preload X-term for step s=1 ---
    float xv[2][4];
    {
        const int sp1 = REV ? 254 : 1;
        #pragma unroll
        for (int mt = 0; mt < 2; ++mt)
            #pragma unroll
            for (int r = 0; r < 4; ++r)
                xv[mt][r] = Yb[gb[mt][r] + (size_t)sp1 * SS];
    }

    for (int s = 1; s < 256; ++s) {
        const int sp = REV ? (255 - s) : s;
        const _Float16* Sr = S[(s - 1) & 1];
        _Float16*       Sw = S[s & 1];

        // prefetch X-term for step s+1 (latency hidden by MFMA+tanh)
        float xn[2][4];
        if (s < 255) {
            const int spn = REV ? (255 - (s + 1)) : (s + 1);
            #pragma unroll
            for (int mt = 0; mt < 2; ++mt)
                #pragma unroll
                for (int r = 0; r < 4; ++r)
                    xn[mt][r] = Yb[gb[mt][r] + (size_t)spn * SS];
        }

        float4v acc0 = {0.f, 0.f, 0.f, 0.f};
        float4v acc1 = {0.f, 0.f, 0.f, 0.f};
        #pragma unroll
        for (int kt = 0; kt < 5; ++kt) {
            // B[k=quad*8+j][n] = state[ch=quad*8+j][pos + kt - 2] (row pos+kt)
            half8 bf = *(const half8*)(Sr + (pos + kt) * P + quad * 8);
            acc0 = __builtin_amdgcn_mfma_f32_16x16x32_f16(afrag[0][kt], bf, acc0, 0, 0, 0);
            acc1 = __builtin_amdgcn_mfma_f32_16x16x32_f16(afrag[1][kt], bf, acc1, 0, 0, 0);
        }

        // epilogue: v = X + tanh(conv + bias); store global + LDS(next buf)
        float v0[4], v1[4];
        #pragma unroll
        for (int r = 0; r < 4; ++r) {
            v0[r] = xv[0][r] + fast_tanh(acc0[r] + bs[0][r]);
            v1[r] = xv[1][r] + fast_tanh(acc1[r] + bs[1][r]);
        }
        #pragma unroll
        for (int r = 0; r < 4; ++r) {
            Yb[gb[0][r] + (size_t)sp * SS] = v0[r];   // fire-and-forget
            Yb[gb[1][r] + (size_t)sp * SS] = v1[r];
        }
        uint2 pk0, pk1;
        pk0.x = packh2(v0[0], v0[1]); pk0.y = packh2(v0[2], v0[3]);
        pk1.x = packh2(v1[0], v1[1]); pk1.y = packh2(v1[2], v1[3]);
        *(uint2*)&Sw[(pos + 2) * P + 0  + quad * 4] = pk0;   // ch = quad*4+r
        *(uint2*)&Sw[(pos + 2) * P + 16 + quad * 4] = pk1;   // ch = 16+quad*4+r

        barrier_lds();   // LDS-only drain: no vmcnt(0) store-ack stall

        #pragma unroll
        for (int mt = 0; mt < 2; ++mt)
            #pragma unroll
            for (int r = 0; r < 4; ++r)
                xv[mt][r] = xn[mt][r];
    }
}

// ---------------------------------------------------------------------------
// Final conv: sigmoid( conv3x3_{32->1}(Y) + b )
__global__ __launch_bounds__(256) void final_conv(
    float* __restrict__ out, const float* __restrict__ Y,
    const float* __restrict__ W, const float* __restrict__ bias)
{
    int bh = blockIdx.x;
    int b  = bh >> 8;
    int h  = bh & 255;
    int x  = threadIdx.x;

    float acc = bias[0];
    for (int ci = 0; ci < CH; ++ci) {
        #pragma unroll
        for (int ky = 0; ky < 3; ++ky) {
            int y = h + ky - 1;
            if ((unsigned)y >= (unsigned)HH) continue;
            #pragma unroll
            for (int kx = 0; kx < 3; ++kx) {
                int xx = x + kx - 1;
                float v = ((unsigned)xx < (unsigned)WW)
                          ? Y[(((size_t)b * CH + ci) * HH + y) * WW + xx] : 0.f;
                acc = fmaf(v, W[(ci * 3 + ky) * 3 + kx], acc);
            }
        }
    }
    float sg = 1.f / (1.f + __expf(-acc));
    out[((size_t)b * HH + h) * WW + x] = sg;
}

// ---------------------------------------------------------------------------
extern "C" void kernel_launch(void* const* d_in, const int* in_sizes, int n_in,
                              void* d_out, int out_size, void* d_ws, size_t ws_size,
                              hipStream_t stream)
{
    const float* X      = (const float*)d_in[0];
    const float* w_init = (const float*)d_in[1];
    const float* b_init = (const float*)d_in[2];
    const float* w_u    = (const float*)d_in[3];
    const float* b_u    = (const float*)d_in[4];
    const float* w_d    = (const float*)d_in[5];
    const float* b_d    = (const float*)d_in[6];
    const float* w_l    = (const float*)d_in[7];
    const float* b_l    = (const float*)d_in[8];
    const float* w_r    = (const float*)d_in[9];
    const float* b_r    = (const float*)d_in[10];
    const float* w_end  = (const float*)d_in[11];
    const float* b_end  = (const float*)d_in[12];
    float* out = (float*)d_out;

    float*    Y  = (float*)d_ws;              // 128 MiB fp32 state
    unsigned* wA = (unsigned*)(Y + YELEMS);   // 10240 dwords f16 A-fragments

    prep_weights<<<dim3(40), dim3(256), 0, stream>>>(wA, w_u, w_d, w_l, w_r);
    init_conv<<<dim3(BB * HH), dim3(256), 0, stream>>>(Y, X, w_init, b_init);

    // up: axis=H, reverse  (r = x: RS=1, s = h: SS=256)
    scan_kernel<1, 256, true ><<<dim3(BB), dim3(1024), 0, stream>>>(Y, wA + 0 * 2560, b_u);
    // down: axis=H, forward
    scan_kernel<1, 256, false><<<dim3(BB), dim3(1024), 0, stream>>>(Y, wA + 1 * 2560, b_d);
    // left: axis=W, reverse (r = h: RS=256, s = w: SS=1)
    scan_kernel<256, 1, true ><<<dim3(BB), dim3(1024), 0, stream>>>(Y, wA + 2 * 2560, b_l);
    // right: axis=W, forward
    scan_kernel<256, 1, false><<<dim3(BB), dim3(1024), 0, stream>>>(Y, wA + 3 * 2560, b_r);

    final_conv<<<dim3(BB * HH), dim3(256), 0, stream>>>(out, Y, w_end, b_end);
}

// Round 6
// 5478.747 us; speedup vs baseline: 1.1861x; 1.1861x over previous
//
#include <hip/hip_runtime.h>
#include <hip/hip_bf16.h>

// Problem constants
#define BB 16
#define CIN 7
#define CH 32
#define HH 256
#define WW 256
#define PLANE (HH*WW)                   // 65536
#define YELEMS ((size_t)BB*CH*PLANE)    // 33,554,432 floats = 128 MiB

typedef _Float16 half2v  __attribute__((ext_vector_type(2)));
typedef _Float16 half8   __attribute__((ext_vector_type(8)));
typedef float    float4v __attribute__((ext_vector_type(4)));

__device__ __forceinline__ float fast_tanh(float x) {
    float xc = fminf(fmaxf(x, -15.f), 15.f);
    float e  = __expf(2.f * xc);
    return (e - 1.f) / (e + 1.f);
}

__device__ __forceinline__ unsigned packh2(float a, float b) {
    half2v h;
    h.x = (_Float16)a;
    h.y = (_Float16)b;
    return __builtin_bit_cast(unsigned, h);
}

// Barrier that drains ONLY LDS (lgkmcnt), not global (vmcnt).
// Safe: the only cross-wave hazard in the step loop is LDS; all global Y
// accesses are lane-private (read-before-write, one touch per column).
// Crucially this lets the 2-step-ahead X prefetch AND the output stores
// stay in flight across barriers (no vmcnt(0) drain per step).
__device__ __forceinline__ void barrier_lds() {
    asm volatile("s_waitcnt lgkmcnt(0)\n\ts_barrier" ::: "memory");
}

// ---------------------------------------------------------------------------
// Pack scan weights (CH,CH,5) fp32 -> f16 A-fragment order for
// v_mfma_f32_16x16x32_f16 (verified correct in rounds 3/4).
__global__ __launch_bounds__(256) void prep_weights(
    unsigned* __restrict__ wA,
    const float* __restrict__ wu, const float* __restrict__ wd,
    const float* __restrict__ wl, const float* __restrict__ wr)
{
    int idx = blockIdx.x * 256 + threadIdx.x;   // dword index [0, 10240)
    if (idx >= 4 * 2560) return;
    int set = idx / 2560;
    int rem = idx % 2560;
    int mt  = rem / 1280;
    int r2  = rem % 1280;
    int kt  = r2 / 256;
    int r3  = r2 % 256;
    int lane = r3 >> 2;
    int jd   = r3 & 3;
    int m    = lane & 15;
    int quad = lane >> 4;
    int ch_out = mt * 16 + m;
    int ch_in0 = quad * 8 + jd * 2;
    const float* src = (set == 0) ? wu : (set == 1) ? wd : (set == 2) ? wl : wr;
    float a = src[(ch_out * CH + ch_in0) * 5 + kt];
    float b = src[(ch_out * CH + ch_in0 + 1) * 5 + kt];
    wA[idx] = packh2(a, b);
}

// ---------------------------------------------------------------------------
// Init conv: Y[b,o,h,x] = tanh( conv3x3(X) + b ), fp32.
__global__ __launch_bounds__(256) void init_conv(
    float* __restrict__ Y, const float* __restrict__ X,
    const float* __restrict__ W, const float* __restrict__ bias)
{
    int bh = blockIdx.x;
    int b  = bh >> 8;
    int h  = bh & 255;
    int x  = threadIdx.x;

    float acc[CH];
    #pragma unroll
    for (int o = 0; o < CH; ++o) acc[o] = bias[o];

    for (int ci = 0; ci < CIN; ++ci) {
        #pragma unroll
        for (int ky = 0; ky < 3; ++ky) {
            int y = h + ky - 1;
            if ((unsigned)y >= (unsigned)HH) continue;
            #pragma unroll
            for (int kx = 0; kx < 3; ++kx) {
                int xx = x + kx - 1;
                float v = ((unsigned)xx < (unsigned)WW)
                          ? X[(((size_t)b * CIN + ci) * HH + y) * WW + xx] : 0.f;
                #pragma unroll
                for (int o = 0; o < CH; ++o)
                    acc[o] = fmaf(v, W[((o * CIN + ci) * 3 + ky) * 3 + kx], acc[o]);
            }
        }
    }
    size_t base = ((size_t)b * CH) * PLANE + (size_t)h * WW + x;
    #pragma unroll
    for (int o = 0; o < CH; ++o)
        Y[base + (size_t)o * PLANE] = fast_tanh(acc[o]);
}

// ---------------------------------------------------------------------------
// MFMA directional scan, in-place on fp32 Y. One block per batch image.
// Identical numerics/structure to the round-3 PASSED kernel; changes:
//  * step loop unrolled x4 with 4 rotating X-register buffers at static
//    distance 2 (no copies -> vmcnt wait lands ~2 steps after issue)
//  * lgkm-only barrier (no per-step vmcnt(0) drain)
template<int RS, int SS, bool REV>
__global__ __launch_bounds__(1024) void scan_kernel(
    float* __restrict__ Y, const unsigned* __restrict__ wA,
    const float* __restrict__ bias)
{
    constexpr int P = 40;                     // halves per LDS row
    __shared__ _Float16 S[2][260 * P];        // rows: logical pos p at row p+2

    const int tid  = threadIdx.x;
    const int wv   = __builtin_amdgcn_readfirstlane(tid >> 6);
    const int lane = tid & 63;
    const int n    = lane & 15;
    const int quad = lane >> 4;
    const int pos  = wv * 16 + n;

    // --- persistent A fragments (weights) ---
    half8 afrag[2][5];
    #pragma unroll
    for (int mt = 0; mt < 2; ++mt)
        #pragma unroll
        for (int kt = 0; kt < 5; ++kt) {
            uint4 u = *(const uint4*)(wA + (((mt * 5 + kt) * 64 + lane) << 2));
            afrag[mt][kt] = __builtin_bit_cast(half8, u);
        }

    // --- per-lane bias and global offsets: ch = mt*16 + quad*4 + r ---
    float bs[2][4];
    size_t gb[2][4];
    float* Yb = Y + (size_t)blockIdx.x * CH * PLANE;
    #pragma unroll
    for (int mt = 0; mt < 2; ++mt)
        #pragma unroll
        for (int r = 0; r < 4; ++r) {
            int ch = mt * 16 + quad * 4 + r;
            bs[mt][r] = bias[ch];
            gb[mt][r] = (size_t)ch * PLANE + (size_t)pos * RS;
        }

    // --- zero pad rows {0,1,258,259} of both buffers ---
    if (tid < 320) {
        int bf  = tid / 160;
        int t   = tid % 160;
        int rr  = t / P;
        int col = t % P;
        int row = (rr < 2) ? rr : (256 + rr);
        S[bf][row * P + col] = (_Float16)0.f;
    }

    // --- initial fill of buf0 with row sp0 (unchanged output row) ---
    {
        const int sp0 = REV ? (HH - 1) : 0;
        int pos0 = tid & 255;
        int cg   = tid >> 8;                  // 0..3 -> channels cg*8..cg*8+7
        float v[8];
        #pragma unroll
        for (int c = 0; c < 8; ++c)
            v[c] = Yb[(size_t)(cg * 8 + c) * PLANE + (size_t)pos0 * RS + (size_t)sp0 * SS];
        uint4 pk;
        pk.x = packh2(v[0], v[1]);
        pk.y = packh2(v[2], v[3]);
        pk.z = packh2(v[4], v[5]);
        pk.w = packh2(v[6], v[7]);
        *(uint4*)&S[0][(pos0 + 2) * P + cg * 8] = pk;
    }
    __syncthreads();

    auto sp_of = [&](int s) { return REV ? (255 - s) : s; };

    // one recurrence step; consumes xin (X row s, loaded >=2 steps ago),
    // issues prefetch loads for row s_pf into xout.
    auto body = [&](int s, float (&xin)[2][4], float (&xout)[2][4], int s_pf) {
        const int sp  = sp_of(s);
        const int spf = sp_of(s_pf > 255 ? 255 : s_pf);

        // issue prefetch FIRST (pure VMEM, no dependency on this step)
        #pragma unroll
        for (int mt = 0; mt < 2; ++mt)
            #pragma unroll
            for (int r = 0; r < 4; ++r)
                xout[mt][r] = Yb[gb[mt][r] + (size_t)spf * SS];

        const _Float16* Sr = S[(s - 1) & 1];
        _Float16*       Sw = S[s & 1];

        float4v acc0 = {0.f, 0.f, 0.f, 0.f};
        float4v acc1 = {0.f, 0.f, 0.f, 0.f};
        #pragma unroll
        for (int kt = 0; kt < 5; ++kt) {
            half8 bf = *(const half8*)(Sr + (pos + kt) * P + quad * 8);
            acc0 = __builtin_amdgcn_mfma_f32_16x16x32_f16(afrag[0][kt], bf, acc0, 0, 0, 0);
            acc1 = __builtin_amdgcn_mfma_f32_16x16x32_f16(afrag[1][kt], bf, acc1, 0, 0, 0);
        }

        float v0[4], v1[4];
        #pragma unroll
        for (int r = 0; r < 4; ++r) {
            v0[r] = xin[0][r] + fast_tanh(acc0[r] + bs[0][r]);
            v1[r] = xin[1][r] + fast_tanh(acc1[r] + bs[1][r]);
        }
        #pragma unroll
        for (int r = 0; r < 4; ++r) {
            Yb[gb[0][r] + (size_t)sp * SS] = v0[r];   // fire-and-forget
            Yb[gb[1][r] + (size_t)sp * SS] = v1[r];
        }
        uint2 pk0, pk1;
        pk0.x = packh2(v0[0], v0[1]); pk0.y = packh2(v0[2], v0[3]);
        pk1.x = packh2(v1[0], v1[1]); pk1.y = packh2(v1[2], v1[3]);
        *(uint2*)&Sw[(pos + 2) * P + 0  + quad * 4] = pk0;   // ch = quad*4+r
        *(uint2*)&Sw[(pos + 2) * P + 16 + quad * 4] = pk1;   // ch = 16+quad*4+r

        barrier_lds();   // LDS-only drain: prefetch & stores stay in flight
    };

    // 4 rotating X buffers, consumed at static distance 2 from their load.
    float x0[2][4], x1[2][4], x2[2][4], x3[2][4];
    {
        const int sp1 = sp_of(1), sp2 = sp_of(2);
        #pragma unroll
        for (int mt = 0; mt < 2; ++mt)
            #pragma unroll
            for (int r = 0; r < 4; ++r) {
                x0[mt][r] = Yb[gb[mt][r] + (size_t)sp1 * SS];
                x1[mt][r] = Yb[gb[mt][r] + (size_t)sp2 * SS];
            }
    }

    // steps 1..252 in chunks of 4; body(t): consume x[(t-1)&3], load x[(t+1)&3]
    for (int s = 1; s <= 249; s += 4) {
        body(s + 0, x0, x2, s + 2);
        body(s + 1, x1, x3, s + 3);
        body(s + 2, x2, x0, s + 4);
        body(s + 3, x3, x1, s + 5);
    }
    // tail: steps 253, 254, 255 (prefetches are clamped dummies)
    body(253, x0, x2, 255);
    body(254, x1, x3, 255);
    body(255, x2, x0, 255);
}

// ---------------------------------------------------------------------------
// Final conv: sigmoid( conv3x3_{32->1}(Y) + b )
__global__ __launch_bounds__(256) void final_conv(
    float* __restrict__ out, const float* __restrict__ Y,
    const float* __restrict__ W, const float* __restrict__ bias)
{
    int bh = blockIdx.x;
    int b  = bh >> 8;
    int h  = bh & 255;
    int x  = threadIdx.x;

    float acc = bias[0];
    for (int ci = 0; ci < CH; ++ci) {
        #pragma unroll
        for (int ky = 0; ky < 3; ++ky) {
            int y = h + ky - 1;
            if ((unsigned)y >= (unsigned)HH) continue;
            #pragma unroll
            for (int kx = 0; kx < 3; ++kx) {
                int xx = x + kx - 1;
                float v = ((unsigned)xx < (unsigned)WW)
                          ? Y[(((size_t)b * CH + ci) * HH + y) * WW + xx] : 0.f;
                acc = fmaf(v, W[(ci * 3 + ky) * 3 + kx], acc);
            }
        }
    }
    float sg = 1.f / (1.f + __expf(-acc));
    out[((size_t)b * HH + h) * WW + x] = sg;
}

// ---------------------------------------------------------------------------
extern "C" void kernel_launch(void* const* d_in, const int* in_sizes, int n_in,
                              void* d_out, int out_size, void* d_ws, size_t ws_size,
                              hipStream_t stream)
{
    const float* X      = (const float*)d_in[0];
    const float* w_init = (const float*)d_in[1];
    const float* b_init = (const float*)d_in[2];
    const float* w_u    = (const float*)d_in[3];
    const float* b_u    = (const float*)d_in[4];
    const float* w_d    = (const float*)d_in[5];
    const float* b_d    = (const float*)d_in[6];
    const float* w_l    = (const float*)d_in[7];
    const float* b_l    = (const float*)d_in[8];
    const float* w_r    = (const float*)d_in[9];
    const float* b_r    = (const float*)d_in[10];
    const float* w_end  = (const float*)d_in[11];
    const float* b_end  = (const float*)d_in[12];
    float* out = (float*)d_out;

    float*    Y  = (float*)d_ws;              // 128 MiB fp32 state
    unsigned* wA = (unsigned*)(Y + YELEMS);   // 10240 dwords f16 A-fragments

    prep_weights<<<dim3(40), dim3(256), 0, stream>>>(wA, w_u, w_d, w_l, w_r);
    init_conv<<<dim3(BB * HH), dim3(256), 0, stream>>>(Y, X, w_init, b_init);

    // up: axis=H, reverse  (r = x: RS=1, s = h: SS=256)
    scan_kernel<1, 256, true ><<<dim3(BB), dim3(1024), 0, stream>>>(Y, wA + 0 * 2560, b_u);
    // down: axis=H, forward
    scan_kernel<1, 256, false><<<dim3(BB), dim3(1024), 0, stream>>>(Y, wA + 1 * 2560, b_d);
    // left: axis=W, reverse (r = h: RS=256, s = w: SS=1)
    scan_kernel<256, 1, true ><<<dim3(BB), dim3(1024), 0, stream>>>(Y, wA + 2 * 2560, b_l);
    // right: axis=W, forward
    scan_kernel<256, 1, false><<<dim3(BB), dim3(1024), 0, stream>>>(Y, wA + 3 * 2560, b_r);

    final_conv<<<dim3(BB * HH), dim3(256), 0, stream>>>(out, Y, w_end, b_end);
}